// Round 2
// baseline (18.231 us; speedup 1.0000x reference)
//
#include <hip/hip_runtime.h>

// out[b,o] = sum_k sbar[b,k] * Meff[k,o]
//   sbar[b,k] = mean_n exp(-(r_bn - 3k/7)^2),  r = ||p - centroid||  (+1e-12 under sqrt)
//   Meff = W1a@W1b@W2a@W2b / sqrt(8*6*6*6), with the 1/128 point-mean folded in.
// The 1o (direction) path and 2e SH basis of the reference are dead code.

__global__ __launch_bounds__(256) void sph_fused(
    const float* __restrict__ pos,
    const float* __restrict__ W1a, const float* __restrict__ W1b,
    const float* __restrict__ W2a, const float* __restrict__ W2b,
    float* __restrict__ out, int nBatch)
{
    __shared__ float BB[36];
    __shared__ float CC[36];
    __shared__ float MM[64];   // padded so OOB lanes (lsub=6,7) stay in-bounds

    const int t = threadIdx.x;

    // ---- build effective 8x6 matrix once per block (tiny) ----
    if (t < 36) {
        const int c = t / 6, o = t - 6 * c;
        float s = 0.f;
        #pragma unroll
        for (int j = 0; j < 6; ++j) s += W2a[c * 6 + j] * W2b[j * 6 + o];
        BB[t] = s;
    }
    __syncthreads();
    if (t < 36) {
        const int c = t / 6, o = t - 6 * c;
        float s = 0.f;
        #pragma unroll
        for (int j = 0; j < 6; ++j) s += W1b[c * 6 + j] * BB[j * 6 + o];
        CC[t] = s;
    }
    __syncthreads();
    if (t < 64) {
        if (t < 48) {
            const int k = t / 6, o = t - 6 * k;
            float s = 0.f;
            #pragma unroll
            for (int c = 0; c < 6; ++c) s += W1a[k * 6 + c] * CC[c * 6 + o];
            // 1/sqrt(8*6*6*6) = 0.024056261..., and fold in the 1/128 point-mean
            MM[t] = s * (0.024056261216234408f / 128.0f);
        } else {
            MM[t] = 0.f;
        }
    }
    __syncthreads();

    // ---- main: one batch per 8 lanes, 16 points (48 floats) per lane ----
    const int lane = t & 63;
    const int wv   = t >> 6;                       // wave in block (0..3)
    const int lsub = lane & 7;                     // lane within batch-group
    const int batch = (blockIdx.x * 4 + wv) * 8 + (lane >> 3);
    if (batch >= nBatch) return;                   // whole 8-lane groups drop together

    union { float4 q[12]; float s[48]; } u;
    const float4* p4 = reinterpret_cast<const float4*>(
        pos + (size_t)batch * 384 + lsub * 48);
    #pragma unroll
    for (int j = 0; j < 12; ++j) u.q[j] = p4[j];

    // centroid: local partial sums, then xor-1/2/4 butterfly within the 8-lane group
    float sx = 0.f, sy = 0.f, sz = 0.f;
    #pragma unroll
    for (int i = 0; i < 16; ++i) {
        sx += u.s[3 * i + 0]; sy += u.s[3 * i + 1]; sz += u.s[3 * i + 2];
    }
    sx += __shfl_xor(sx, 1, 64); sy += __shfl_xor(sy, 1, 64); sz += __shfl_xor(sz, 1, 64);
    sx += __shfl_xor(sx, 2, 64); sy += __shfl_xor(sy, 2, 64); sz += __shfl_xor(sz, 2, 64);
    sx += __shfl_xor(sx, 4, 64); sy += __shfl_xor(sy, 4, 64); sz += __shfl_xor(sz, 4, 64);
    const float mx = sx * (1.f / 128.f), my = sy * (1.f / 128.f), mz = sz * (1.f / 128.f);

    // per-point radius + 8 RBFs, accumulate local sums
    float acc[8] = {0.f, 0.f, 0.f, 0.f, 0.f, 0.f, 0.f, 0.f};
    #pragma unroll
    for (int i = 0; i < 16; ++i) {
        const float dx = u.s[3 * i + 0] - mx;
        const float dy = u.s[3 * i + 1] - my;
        const float dz = u.s[3 * i + 2] - mz;
        const float r = sqrtf(dx * dx + dy * dy + dz * dz + 1e-12f);
        #pragma unroll
        for (int k = 0; k < 8; ++k) {
            const float d = r - (float)k * (3.0f / 7.0f);
            acc[k] += __expf(-(d * d));
        }
    }

    // 8-value sum across the 8-lane group via value-split butterflies (7 shuffles).
    // After xor-1: lane bit0=b holds pair-sums of acc[2j+b].
    // After xor-2: acc[4j+2*b1+b0].  After xor-4: lane lsub holds total acc[lsub].
    const int l0 = lsub & 1, l1 = (lsub >> 1) & 1, l2 = (lsub >> 2) & 1;
    float bj[4];
    #pragma unroll
    for (int j = 0; j < 4; ++j) {
        const float send = l0 ? acc[2 * j]     : acc[2 * j + 1];
        const float keep = l0 ? acc[2 * j + 1] : acc[2 * j];
        bj[j] = keep + __shfl_xor(send, 1, 64);
    }
    float cj[2];
    #pragma unroll
    for (int j = 0; j < 2; ++j) {
        const float send = l1 ? bj[2 * j]     : bj[2 * j + 1];
        const float keep = l1 ? bj[2 * j + 1] : bj[2 * j];
        cj[j] = keep + __shfl_xor(send, 2, 64);
    }
    float S;
    {
        const float send = l2 ? cj[0] : cj[1];
        const float keep = l2 ? cj[1] : cj[0];
        S = keep + __shfl_xor(send, 4, 64);
    }
    // lane lsub now holds the batch-total of acc[lsub] (identity mapping)

    // 8x6 matvec: gather S_k from lane (laneBase + k), dot with MM column
    const int laneBase = lane & 56;
    float oacc = 0.f;
    #pragma unroll
    for (int k = 0; k < 8; ++k) {
        const float sk = __shfl(S, laneBase + k, 64);
        oacc += sk * MM[k * 6 + lsub];
    }
    if (lsub < 6) out[batch * 6 + lsub] = oacc;
}

extern "C" void kernel_launch(void* const* d_in, const int* in_sizes, int n_in,
                              void* d_out, int out_size, void* d_ws, size_t ws_size,
                              hipStream_t stream) {
    const float* pos = (const float*)d_in[0];
    const float* W1a = (const float*)d_in[1];
    const float* W1b = (const float*)d_in[2];
    const float* W2a = (const float*)d_in[5];
    const float* W2b = (const float*)d_in[6];
    float* out = (float*)d_out;

    const int nBatch = in_sizes[0] / 384;          // 32768 for the bench shape
    const int batchesPerBlock = 32;                // 4 waves x 8 batches
    const int grid = (nBatch + batchesPerBlock - 1) / batchesPerBlock;

    sph_fused<<<dim3(grid), dim3(256), 0, stream>>>(pos, W1a, W1b, W2a, W2b, out, nBatch);
}

// Round 3
// 17.422 us; speedup vs baseline: 1.0464x; 1.0464x over previous
//
#include <hip/hip_runtime.h>

// out[b,o] = sum_k sbar[b,k] * Meff[k,o]
//   sbar[b,k] = mean_n exp(-(r_bn - 3k/7)^2),  r = ||p - centroid|| (+1e-12 under sqrt)
//   Meff = W1a@W1b@W2a@W2b / sqrt(8*6*6*6), 1/128 point-mean folded in.
// RBF refactor: exp(-(r-ck)^2) = e^{-r^2} * e^{-ck^2} * (e^{6r/7})^k  -> 2 exps/point.
// Layout: 1 batch per 16 lanes, 8 points/lane. Global loads are wave-contiguous
// float4 (fully coalesced); an in-wave LDS pass (XOR-swizzled) redistributes
// chunks so each lane owns 24 contiguous floats. No __syncthreads needed for
// staging (wave-private LDS region; DS ops complete in-order per wave).

__global__ __launch_bounds__(256) void sph_fused(
    const float* __restrict__ pos,
    const float* __restrict__ W1a, const float* __restrict__ W1b,
    const float* __restrict__ W2a, const float* __restrict__ W2b,
    float* __restrict__ out, int nBatch)
{
    __shared__ float BB[36];
    __shared__ float CC[36];
    __shared__ float MM[64];            // 8x6 padded; MM[48..63]=0
    __shared__ float4 stage[4][384];    // per-wave 6 KB staging (6 slots x 64 chunks)

    const int t = threadIdx.x;

    // ---- effective 8x6 matrix (tiny, once per block) ----
    if (t < 36) {
        const int c = t / 6, o = t - 6 * c;
        float s = 0.f;
        #pragma unroll
        for (int j = 0; j < 6; ++j) s += W2a[c * 6 + j] * W2b[j * 6 + o];
        BB[t] = s;
    }
    __syncthreads();
    if (t < 36) {
        const int c = t / 6, o = t - 6 * c;
        float s = 0.f;
        #pragma unroll
        for (int j = 0; j < 6; ++j) s += W1b[c * 6 + j] * BB[j * 6 + o];
        CC[t] = s;
    }
    __syncthreads();
    if (t < 64) {
        if (t < 48) {
            const int k = t / 6, o = t - 6 * k;
            float s = 0.f;
            #pragma unroll
            for (int c = 0; c < 6; ++c) s += W1a[k * 6 + c] * CC[c * 6 + o];
            MM[t] = s * (0.024056261216234408f / 128.0f);  // 1/sqrt(1728) * 1/128
        } else {
            MM[t] = 0.f;
        }
    }
    __syncthreads();   // all barriers before any early return

    const int w    = t >> 6;                     // wave in block (0..3)
    const int lane = t & 63;
    const int wave = blockIdx.x * 4 + w;
    const int wbatch = wave * 4;                 // 4 batches per wave
    if (wbatch >= nBatch) return;

    // ---- stage 6 KB coalesced -> LDS (xor-swizzled), redistribute in-wave ----
    const int nChunks = nBatch * 96;             // float4 chunks total
    const int wchunk  = wave * 384;
    const float4* p4 = reinterpret_cast<const float4*>(pos);
    #pragma unroll
    for (int j = 0; j < 6; ++j) {
        const int q = j * 64 + lane;             // local chunk 0..383
        int gc = wchunk + q;
        if (gc >= nChunks) gc = nChunks - 1;     // clamp (stores are guarded)
        const float4 v = p4[gc];                 // lane-contiguous: coalesced
        const int o = (q * 171) >> 10;           // q / 6  (owner lane)
        const int s = q - 6 * o;                 // q % 6  (slot)
        stage[w][s * 64 + (o ^ s)] = v;          // xor-swizzle: CF reads
    }
    // writes/reads are same-wave; DS completes in-order. Fence the compiler.
    asm volatile("s_waitcnt lgkmcnt(0)" ::: "memory");

    union { float4 q4[6]; float f[24]; } u;      // this lane's 8 points
    #pragma unroll
    for (int s = 0; s < 6; ++s) u.q4[s] = stage[w][s * 64 + (lane ^ s)];

    // ---- centroid over the 16-lane batch group ----
    float sx = 0.f, sy = 0.f, sz = 0.f;
    #pragma unroll
    for (int i = 0; i < 8; ++i) {
        sx += u.f[3 * i + 0]; sy += u.f[3 * i + 1]; sz += u.f[3 * i + 2];
    }
    #pragma unroll
    for (int m = 1; m <= 8; m <<= 1) {
        sx += __shfl_xor(sx, m, 64);
        sy += __shfl_xor(sy, m, 64);
        sz += __shfl_xor(sz, m, 64);
    }
    const float mx = sx * (1.f / 128.f), my = sy * (1.f / 128.f), mz = sz * (1.f / 128.f);

    // ---- RBFs: 2 exps per point ----
    // wk = exp(-(3k/7)^2)
    const float WK1 = 0.83220583f, WK2 = 0.47965235f, WK3 = 0.19146295f,
                WK4 = 0.05293049f, WK5 = 0.01013418f, WK6 = 0.00134381f,
                WK7 = 1.2340980e-4f;
    float acc[8] = {0.f, 0.f, 0.f, 0.f, 0.f, 0.f, 0.f, 0.f};
    #pragma unroll
    for (int i = 0; i < 8; ++i) {
        const float dx = u.f[3 * i + 0] - mx;
        const float dy = u.f[3 * i + 1] - my;
        const float dz = u.f[3 * i + 2] - mz;
        const float r2 = fmaf(dx, dx, fmaf(dy, dy, fmaf(dz, dz, 1e-12f)));
        const float r  = sqrtf(r2);
        const float E0 = __expf(-r2);                 // e^{-r^2}
        const float Bf = __expf(r * (6.0f / 7.0f));   // e^{6r/7}
        float p = E0;
        acc[0] += E0;
        p *= Bf; acc[1] = fmaf(p, WK1, acc[1]);
        p *= Bf; acc[2] = fmaf(p, WK2, acc[2]);
        p *= Bf; acc[3] = fmaf(p, WK3, acc[3]);
        p *= Bf; acc[4] = fmaf(p, WK4, acc[4]);
        p *= Bf; acc[5] = fmaf(p, WK5, acc[5]);
        p *= Bf; acc[6] = fmaf(p, WK6, acc[6]);
        p *= Bf; acc[7] = fmaf(p, WK7, acc[7]);
    }

    // ---- 8-value sum over the 16-lane group (value-split butterflies) ----
    const int lsub = lane & 15;
    const int l0 = lsub & 1, l1 = (lsub >> 1) & 1, l2 = (lsub >> 2) & 1;
    float bj[4];
    #pragma unroll
    for (int j = 0; j < 4; ++j) {
        const float send = l0 ? acc[2 * j]     : acc[2 * j + 1];
        const float keep = l0 ? acc[2 * j + 1] : acc[2 * j];
        bj[j] = keep + __shfl_xor(send, 1, 64);
    }
    float cj[2];
    #pragma unroll
    for (int j = 0; j < 2; ++j) {
        const float send = l1 ? bj[2 * j]     : bj[2 * j + 1];
        const float keep = l1 ? bj[2 * j + 1] : bj[2 * j];
        cj[j] = keep + __shfl_xor(send, 2, 64);
    }
    float S;
    {
        const float send = l2 ? cj[0] : cj[1];
        const float keep = l2 ? cj[1] : cj[0];
        S = keep + __shfl_xor(send, 4, 64);
    }
    S += __shfl_xor(S, 8, 64);
    // lane (group, lsub) holds batch-total of acc[lsub & 7]

    // ---- 8x6 matvec ----
    const int gb = lane & 48;
    float oacc = 0.f;
    #pragma unroll
    for (int k = 0; k < 8; ++k)
        oacc = fmaf(__shfl(S, gb + k, 64), MM[k * 6 + lsub], oacc);

    // ---- store: wave's 24 consecutive outputs via lanes 0..23 ----
    const int LL = (lane < 24) ? lane : 0;
    const int g = LL / 6, r = LL - 6 * g;
    const float val = __shfl(oacc, g * 16 + r, 64);
    if (lane < 24 && (wbatch + g) < nBatch) out[wbatch * 6 + lane] = val;
}

extern "C" void kernel_launch(void* const* d_in, const int* in_sizes, int n_in,
                              void* d_out, int out_size, void* d_ws, size_t ws_size,
                              hipStream_t stream) {
    const float* pos = (const float*)d_in[0];
    const float* W1a = (const float*)d_in[1];
    const float* W1b = (const float*)d_in[2];
    const float* W2a = (const float*)d_in[5];
    const float* W2b = (const float*)d_in[6];
    float* out = (float*)d_out;

    const int nBatch = in_sizes[0] / 384;        // 32768 for the bench shape
    const int batchesPerBlock = 16;              // 4 waves x 4 batches
    const int grid = (nBatch + batchesPerBlock - 1) / batchesPerBlock;

    sph_fused<<<dim3(grid), dim3(256), 0, stream>>>(pos, W1a, W1b, W2a, W2b, out, nBatch);
}

// Round 4
// 15.554 us; speedup vs baseline: 1.1721x; 1.1201x over previous
//
#include <hip/hip_runtime.h>

// out[b,o] = sum_k sbar[b,k] * Meff[k,o]
//   sbar[b,k] = mean_n exp(-(r_bn - 3k/7)^2),  r = ||p - centroid|| (+1e-12 under sqrt)
//   Meff = W1a@W1b@W2a@W2b / sqrt(8*6*6*6), 1/128 point-mean folded in.
// RBF refactor: exp(-(r-ck)^2) = e^{-r^2} * e^{-ck^2} * (e^{6r/7})^k -> 2 exps/point.
//
// v4 structure: 1 batch per 16-lane DPP row, 8 points/lane, register
// double-buffered tile pipeline (prefetch t+1 while computing t), ALL
// reductions via v_mov_b32_dpp row_ror (no DS ops, no LDS in the main loop).

template <int N>
__device__ __forceinline__ float ror16(float v) {
    // v_mov_b32_dpp row_ror:N  (rotate within each 16-lane row)
    return __int_as_float(__builtin_amdgcn_update_dpp(
        0, __float_as_int(v), 0x120 | N, 0xF, 0xF, true));
}
__device__ __forceinline__ float rowsum16(float v) {
    v += ror16<1>(v);
    v += ror16<2>(v);
    v += ror16<4>(v);
    v += ror16<8>(v);
    return v;   // every lane in the row holds the 16-lane total
}

__global__ __launch_bounds__(256, 4) void sph_fused(
    const float* __restrict__ pos,
    const float* __restrict__ W1a, const float* __restrict__ W1b,
    const float* __restrict__ W2a, const float* __restrict__ W2b,
    float* __restrict__ out, int nBatch)
{
    __shared__ float BBs[36];
    __shared__ float CCs[36];
    __shared__ float MMs[48];

    const int t = threadIdx.x;

    // ---- effective 8x6 matrix (once per block; blocks are long-lived now) ----
    if (t < 36) {
        const int c = t / 6, o = t - 6 * c;
        float s = 0.f;
        #pragma unroll
        for (int j = 0; j < 6; ++j) s += W2a[c * 6 + j] * W2b[j * 6 + o];
        BBs[t] = s;
    }
    __syncthreads();
    if (t < 36) {
        const int c = t / 6, o = t - 6 * c;
        float s = 0.f;
        #pragma unroll
        for (int j = 0; j < 6; ++j) s += W1b[c * 6 + j] * BBs[j * 6 + o];
        CCs[t] = s;
    }
    __syncthreads();
    if (t < 48) {
        const int k = t / 6, o = t - 6 * k;
        float s = 0.f;
        #pragma unroll
        for (int c = 0; c < 6; ++c) s += W1a[k * 6 + c] * CCs[c * 6 + o];
        MMs[t] = s * (0.024056261216234408f / 128.0f);  // 1/sqrt(1728) * 1/128
    }
    __syncthreads();   // last barrier before any early return

    const int lane = t & 63;
    const int w    = t >> 6;
    const int lsub = lane & 15;          // lane within 16-lane batch row
    const int grp  = lane >> 4;          // batch row within wave (0..3)

    // per-lane copy of this output column of Meff (k = 0..7)
    const int col = (lsub < 6) ? lsub : 0;
    float Mcol[8];
    #pragma unroll
    for (int k = 0; k < 8; ++k) Mcol[k] = MMs[k * 6 + col];

    const int nTiles = (nBatch + 3) >> 2;        // 4 batches per tile
    const int nWaves = gridDim.x * 4;
    int tile = blockIdx.x * 4 + w;
    if (tile >= nTiles) return;

    const float4* __restrict__ p4 = reinterpret_cast<const float4*>(pos);
    const int maxC = nBatch * 96 - 6;            // last valid per-lane base chunk

    union Pts { float4 q[6]; float f[24]; };
    Pts A, B;

    // wk = exp(-(3k/7)^2)
    const float WK1 = 0.83220583f, WK2 = 0.47965235f, WK3 = 0.19146295f,
                WK4 = 0.05293049f, WK5 = 0.01013418f, WK6 = 0.00134381f,
                WK7 = 1.2340980e-4f;

#define LOADT(U, T) do {                                                   \
    int base_ = (T) * 384 + grp * 96 + lsub * 6;                           \
    if (base_ > maxC) base_ = maxC;   /* partial-tile clamp; stores guarded */ \
    _Pragma("unroll")                                                      \
    for (int j_ = 0; j_ < 6; ++j_) (U).q[j_] = p4[base_ + j_];             \
} while (0)

#define COMPUTE(U, T) do {                                                 \
    float sx_ = 0.f, sy_ = 0.f, sz_ = 0.f;                                 \
    _Pragma("unroll")                                                      \
    for (int i_ = 0; i_ < 8; ++i_) {                                       \
        sx_ += (U).f[3 * i_ + 0];                                          \
        sy_ += (U).f[3 * i_ + 1];                                          \
        sz_ += (U).f[3 * i_ + 2];                                          \
    }                                                                      \
    sx_ = rowsum16(sx_); sy_ = rowsum16(sy_); sz_ = rowsum16(sz_);         \
    const float mx_ = sx_ * (1.f / 128.f);                                 \
    const float my_ = sy_ * (1.f / 128.f);                                 \
    const float mz_ = sz_ * (1.f / 128.f);                                 \
    float a0_=0.f,a1_=0.f,a2_=0.f,a3_=0.f,a4_=0.f,a5_=0.f,a6_=0.f,a7_=0.f; \
    _Pragma("unroll")                                                      \
    for (int i_ = 0; i_ < 8; ++i_) {                                       \
        const float dx_ = (U).f[3 * i_ + 0] - mx_;                         \
        const float dy_ = (U).f[3 * i_ + 1] - my_;                         \
        const float dz_ = (U).f[3 * i_ + 2] - mz_;                         \
        const float r2_ = fmaf(dx_, dx_, fmaf(dy_, dy_, fmaf(dz_, dz_, 1e-12f))); \
        float r_;                                                          \
        asm("v_sqrt_f32 %0, %1" : "=v"(r_) : "v"(r2_));                    \
        const float E0_ = __expf(-r2_);                                    \
        const float Bf_ = __expf(r_ * (6.0f / 7.0f));                      \
        float p_ = E0_;                                                    \
        a0_ += E0_;                                                        \
        p_ *= Bf_; a1_ = fmaf(p_, WK1, a1_);                               \
        p_ *= Bf_; a2_ = fmaf(p_, WK2, a2_);                               \
        p_ *= Bf_; a3_ = fmaf(p_, WK3, a3_);                               \
        p_ *= Bf_; a4_ = fmaf(p_, WK4, a4_);                               \
        p_ *= Bf_; a5_ = fmaf(p_, WK5, a5_);                               \
        p_ *= Bf_; a6_ = fmaf(p_, WK6, a6_);                               \
        p_ *= Bf_; a7_ = fmaf(p_, WK7, a7_);                               \
    }                                                                      \
    a0_ = rowsum16(a0_); a1_ = rowsum16(a1_);                              \
    a2_ = rowsum16(a2_); a3_ = rowsum16(a3_);                              \
    a4_ = rowsum16(a4_); a5_ = rowsum16(a5_);                              \
    a6_ = rowsum16(a6_); a7_ = rowsum16(a7_);                              \
    float o_ = a0_ * Mcol[0];                                              \
    o_ = fmaf(a1_, Mcol[1], o_); o_ = fmaf(a2_, Mcol[2], o_);              \
    o_ = fmaf(a3_, Mcol[3], o_); o_ = fmaf(a4_, Mcol[4], o_);              \
    o_ = fmaf(a5_, Mcol[5], o_); o_ = fmaf(a6_, Mcol[6], o_);              \
    o_ = fmaf(a7_, Mcol[7], o_);                                           \
    const int batch_ = (T) * 4 + grp;                                      \
    if (lsub < 6 && batch_ < nBatch) out[batch_ * 6 + lsub] = o_;          \
} while (0)

    // ---- register double-buffered tile pipeline ----
    LOADT(A, tile);
    for (;;) {
        int tn = tile + nWaves;
        if (tn < nTiles) {
            LOADT(B, tn);          // prefetch next tile into B
            COMPUTE(A, tile);      // compute current (loads of B stay in flight)
        } else {
            COMPUTE(A, tile);
            break;
        }
        tile = tn; tn = tile + nWaves;
        if (tn < nTiles) {
            LOADT(A, tn);
            COMPUTE(B, tile);
        } else {
            COMPUTE(B, tile);
            break;
        }
        tile = tn;
    }
#undef LOADT
#undef COMPUTE
}

extern "C" void kernel_launch(void* const* d_in, const int* in_sizes, int n_in,
                              void* d_out, int out_size, void* d_ws, size_t ws_size,
                              hipStream_t stream) {
    const float* pos = (const float*)d_in[0];
    const float* W1a = (const float*)d_in[1];
    const float* W1b = (const float*)d_in[2];
    const float* W2a = (const float*)d_in[5];
    const float* W2b = (const float*)d_in[6];
    float* out = (float*)d_out;

    const int nBatch = in_sizes[0] / 384;        // 32768 for the bench shape
    const int nTiles = (nBatch + 3) / 4;
    int grid = (nTiles + 3) / 4;                 // 4 waves per block
    if (grid > 1024) grid = 1024;                // grid-stride: 2 tiles/wave at bench shape

    sph_fused<<<dim3(grid), dim3(256), 0, stream>>>(pos, W1a, W1b, W2a, W2b, out, nBatch);
}

// Round 5
// 14.956 us; speedup vs baseline: 1.2190x; 1.0400x over previous
//
#include <hip/hip_runtime.h>

// out[b,o] = sum_k sbar[b,k] * Meff[k,o]
//   sbar[b,k] = mean_n exp(-(r_bn - 3k/7)^2),  r = ||p - centroid|| (+1e-12 under sqrt)
//   Meff = W1a@W1b@W2a@W2b / sqrt(8*6*6*6), with 1/128 point-mean AND the
//   RBF constants wk = exp(-(3k/7)^2) folded into row k.
// RBF refactor: exp(-(r-ck)^2) = wk * e^{-r^2} * (e^{6r/7})^k -> 2 exps/point.
//
// v5 structure: max-occupancy one-shot streaming. 32 waves/CU
// (__launch_bounds__(256,8) -> <=64 VGPR), one 6 KB tile (4 batches) per wave,
// 1 batch per 16-lane DPP row, 8 points/lane, all reductions via
// v_mov_b32_dpp row_ror (zero DS ops in the hot path). Mcol is read from LDS
// only after the point registers are dead to minimize live range.

template <int N>
__device__ __forceinline__ float ror16(float v) {
    // v_mov_b32_dpp row_ror:N (rotate within each 16-lane row)
    return __int_as_float(__builtin_amdgcn_update_dpp(
        0, __float_as_int(v), 0x120 | N, 0xF, 0xF, true));
}
__device__ __forceinline__ float rowsum16(float v) {
    v += ror16<1>(v);
    v += ror16<2>(v);
    v += ror16<4>(v);
    v += ror16<8>(v);
    return v;   // every lane in the row holds the 16-lane total
}

__global__ __launch_bounds__(256, 8) void sph_fused(
    const float* __restrict__ pos,
    const float* __restrict__ W1a, const float* __restrict__ W1b,
    const float* __restrict__ W2a, const float* __restrict__ W2b,
    float* __restrict__ out, int nBatch)
{
    __shared__ float BBs[36];
    __shared__ float CCs[36];
    __shared__ float MMs[48];

    const int t = threadIdx.x;

    // ---- effective 8x6 matrix, wk folded into row k (tiny, once per block) ----
    if (t < 36) {
        const int c = t / 6, o = t - 6 * c;
        float s = 0.f;
        #pragma unroll
        for (int j = 0; j < 6; ++j) s += W2a[c * 6 + j] * W2b[j * 6 + o];
        BBs[t] = s;
    }
    __syncthreads();
    if (t < 36) {
        const int c = t / 6, o = t - 6 * c;
        float s = 0.f;
        #pragma unroll
        for (int j = 0; j < 6; ++j) s += W1b[c * 6 + j] * BBs[j * 6 + o];
        CCs[t] = s;
    }
    __syncthreads();
    if (t < 48) {
        const int k = t / 6, o = t - 6 * k;
        float s = 0.f;
        #pragma unroll
        for (int c = 0; c < 6; ++c) s += W1a[k * 6 + c] * CCs[c * 6 + o];
        // wk = exp(-(3k/7)^2), k = t/6
        const float WKtab[8] = {1.0f, 0.83220583f, 0.47965235f, 0.19146295f,
                                0.05293049f, 0.01013418f, 0.00134381f, 1.2340980e-4f};
        MMs[t] = s * WKtab[k] * (0.024056261216234408f / 128.0f); // 1/sqrt(1728)/128
    }
    __syncthreads();   // last barrier before any early return

    const int lane = t & 63;
    const int w    = t >> 6;
    const int lsub = lane & 15;          // lane within 16-lane batch row
    const int grp  = lane >> 4;          // batch row within wave (0..3)

    const int nTiles = (nBatch + 3) >> 2;        // 4 batches per tile
    const int tile = blockIdx.x * 4 + w;
    if (tile >= nTiles) return;

    const float4* __restrict__ p4 = reinterpret_cast<const float4*>(pos);
    int base = tile * 384 + grp * 96 + lsub * 6;
    const int maxC = nBatch * 96 - 6;
    if (base > maxC) base = maxC;        // partial-tile clamp; stores guarded

    union { float4 q[6]; float f[24]; } u;
    #pragma unroll
    for (int j = 0; j < 6; ++j) u.q[j] = p4[base + j];

    // ---- centroid over the 16-lane batch row ----
    float sx = 0.f, sy = 0.f, sz = 0.f;
    #pragma unroll
    for (int i = 0; i < 8; ++i) {
        sx += u.f[3 * i + 0]; sy += u.f[3 * i + 1]; sz += u.f[3 * i + 2];
    }
    sx = rowsum16(sx); sy = rowsum16(sy); sz = rowsum16(sz);
    const float mx = sx * (1.f / 128.f), my = sy * (1.f / 128.f), mz = sz * (1.f / 128.f);

    // ---- RBFs: 2 exps + 1 sqrt per point; wk deferred to the matrix ----
    float a0 = 0.f, a1 = 0.f, a2 = 0.f, a3 = 0.f,
          a4 = 0.f, a5 = 0.f, a6 = 0.f, a7 = 0.f;
    #pragma unroll
    for (int i = 0; i < 8; ++i) {
        const float dx = u.f[3 * i + 0] - mx;
        const float dy = u.f[3 * i + 1] - my;
        const float dz = u.f[3 * i + 2] - mz;
        const float r2 = fmaf(dx, dx, fmaf(dy, dy, fmaf(dz, dz, 1e-12f)));
        float r;
        asm("v_sqrt_f32 %0, %1" : "=v"(r) : "v"(r2));
        const float E0 = __expf(-r2);                 // e^{-r^2}
        const float Bf = __expf(r * (6.0f / 7.0f));   // e^{6r/7}
        float p = E0;
        a0 += E0;
        p *= Bf; a1 += p;
        p *= Bf; a2 += p;
        p *= Bf; a3 += p;
        p *= Bf; a4 += p;
        p *= Bf; a5 += p;
        p *= Bf; a6 += p;
        p *= Bf; a7 += p;
    }
    a0 = rowsum16(a0); a1 = rowsum16(a1); a2 = rowsum16(a2); a3 = rowsum16(a3);
    a4 = rowsum16(a4); a5 = rowsum16(a5); a6 = rowsum16(a6); a7 = rowsum16(a7);

    // ---- 8x6 matvec: Mcol read from LDS now (point regs dead) ----
    const int col = (lsub < 6) ? lsub : 0;
    float o_ = a0 * MMs[0 * 6 + col];
    o_ = fmaf(a1, MMs[1 * 6 + col], o_);
    o_ = fmaf(a2, MMs[2 * 6 + col], o_);
    o_ = fmaf(a3, MMs[3 * 6 + col], o_);
    o_ = fmaf(a4, MMs[4 * 6 + col], o_);
    o_ = fmaf(a5, MMs[5 * 6 + col], o_);
    o_ = fmaf(a6, MMs[6 * 6 + col], o_);
    o_ = fmaf(a7, MMs[7 * 6 + col], o_);

    const int batch = tile * 4 + grp;
    if (lsub < 6 && batch < nBatch) out[batch * 6 + lsub] = o_;
}

extern "C" void kernel_launch(void* const* d_in, const int* in_sizes, int n_in,
                              void* d_out, int out_size, void* d_ws, size_t ws_size,
                              hipStream_t stream) {
    const float* pos = (const float*)d_in[0];
    const float* W1a = (const float*)d_in[1];
    const float* W1b = (const float*)d_in[2];
    const float* W2a = (const float*)d_in[5];
    const float* W2b = (const float*)d_in[6];
    float* out = (float*)d_out;

    const int nBatch = in_sizes[0] / 384;        // 32768 for the bench shape
    const int nTiles = (nBatch + 3) / 4;
    const int grid = (nTiles + 3) / 4;           // one tile per wave, 4 waves/block

    sph_fused<<<dim3(grid), dim3(256), 0, stream>>>(pos, W1a, W1b, W2a, W2b, out, nBatch);
}